// Round 1
// baseline (1600.056 us; speedup 1.0000x reference)
//
#include <hip/hip_runtime.h>
#include <cstdint>
#include <cstddef>

#define N_NODES 100000
#define N_EDGES 1600000
#define N_EVAL  200000

// ---------------- degree / normalization ----------------

__global__ void count_deg_kernel(const int* __restrict__ dst, int* __restrict__ deg, int E) {
    int i = blockIdx.x * blockDim.x + threadIdx.x;
    if (i < E) atomicAdd(&deg[dst[i]], 1);
}

__global__ void dis_kernel(const int* __restrict__ deg, float* __restrict__ dis, int N) {
    int i = blockIdx.x * blockDim.x + threadIdx.x;
    if (i < N) dis[i] = rsqrtf((float)deg[i] + 1.0f);
}

// Single-block exclusive scan of deg -> offsets (N+1 entries).
__global__ __launch_bounds__(1024) void scan_kernel(const int* __restrict__ deg,
                                                    int* __restrict__ offsets, int N, int E) {
    __shared__ int sums[1024];
    int t = threadIdx.x;
    int C = (N + 1023) >> 10;
    int lo = t * C;
    int hi = min(lo + C, N);
    int s = 0;
    for (int i = lo; i < hi; ++i) s += deg[i];
    sums[t] = s;
    __syncthreads();
    for (int d = 1; d < 1024; d <<= 1) {
        int add = (t >= d) ? sums[t - d] : 0;
        __syncthreads();
        sums[t] += add;
        __syncthreads();
    }
    int run = sums[t] - s;           // exclusive prefix for this thread's chunk
    for (int i = lo; i < hi; ++i) { offsets[i] = run; run += deg[i]; }
    if (hi >= N) offsets[N] = E;
}

__global__ void fill_csr_kernel(const int* __restrict__ src, const int* __restrict__ dst,
                                const float* __restrict__ dis, int* __restrict__ cursor,
                                int* __restrict__ csr_src, float* __restrict__ csr_w, int E) {
    int e = blockIdx.x * blockDim.x + threadIdx.x;
    if (e < E) {
        int s = src[e], d = dst[e];
        int p = atomicAdd(&cursor[d], 1);
        csr_src[p] = s;
        csr_w[p] = dis[s] * dis[d];
    }
}

// ---------------- fp32 GEMM: C[M,N] = A[M,K] @ W[K,N] ----------------
// BM=128, BN=128, BK=16, 256 threads, 8x8 micro-tile per thread.

__global__ __launch_bounds__(256) void gemm_f32_kernel(
    const float* __restrict__ A, const float* __restrict__ W,
    float* __restrict__ C, int M, int N, int K)
{
    __shared__ float As[16][128];
    __shared__ float Ws[16][128];
    const int tid = threadIdx.x;
    const int m0 = blockIdx.x * 128;
    const int n0 = blockIdx.y * 128;
    const int ty = tid >> 4;         // 0..15
    const int tx = tid & 15;         // 0..15
    const int ar = tid >> 1;         // 0..127 (A row within tile)
    const int ak = (tid & 1) << 3;   // 0 or 8 (A k sub-offset)
    const int wr = tid >> 4;         // 0..15  (W row within k-tile)
    const int wc = (tid & 15) << 3;  // 0..120 (W col)

    float acc[8][8];
#pragma unroll
    for (int i = 0; i < 8; ++i)
#pragma unroll
        for (int j = 0; j < 8; ++j) acc[i][j] = 0.f;

    const int grow = m0 + ar;
    const float* Aptr = A + (size_t)grow * K + ak;
    const float* Wptr = W + (size_t)wr * N + n0 + wc;

    for (int k0 = 0; k0 < K; k0 += 16) {
        float4 a0, a1;
        if (grow < M) {
            a0 = *(const float4*)(Aptr + k0);
            a1 = *(const float4*)(Aptr + k0 + 4);
        } else {
            a0 = make_float4(0.f, 0.f, 0.f, 0.f);
            a1 = a0;
        }
        float4 w0 = *(const float4*)(Wptr + (size_t)k0 * N);
        float4 w1 = *(const float4*)(Wptr + (size_t)k0 * N + 4);
        As[ak + 0][ar] = a0.x; As[ak + 1][ar] = a0.y; As[ak + 2][ar] = a0.z; As[ak + 3][ar] = a0.w;
        As[ak + 4][ar] = a1.x; As[ak + 5][ar] = a1.y; As[ak + 6][ar] = a1.z; As[ak + 7][ar] = a1.w;
        *(float4*)&Ws[wr][wc]     = w0;
        *(float4*)&Ws[wr][wc + 4] = w1;
        __syncthreads();
#pragma unroll
        for (int kk = 0; kk < 16; ++kk) {
            float a[8], b[8];
            *(float4*)(a)     = *(const float4*)&As[kk][ty * 8];
            *(float4*)(a + 4) = *(const float4*)&As[kk][ty * 8 + 4];
            *(float4*)(b)     = *(const float4*)&Ws[kk][tx * 8];
            *(float4*)(b + 4) = *(const float4*)&Ws[kk][tx * 8 + 4];
#pragma unroll
            for (int i = 0; i < 8; ++i)
#pragma unroll
                for (int j = 0; j < 8; ++j)
                    acc[i][j] = fmaf(a[i], b[j], acc[i][j]);
        }
        __syncthreads();
    }

#pragma unroll
    for (int i = 0; i < 8; ++i) {
        int row = m0 + ty * 8 + i;
        if (row < M) {
            float* cp = C + (size_t)row * N + n0 + tx * 8;
            *(float4*)(cp)     = make_float4(acc[i][0], acc[i][1], acc[i][2], acc[i][3]);
            *(float4*)(cp + 4) = make_float4(acc[i][4], acc[i][5], acc[i][6], acc[i][7]);
        }
    }
}

// ---------------- aggregation: OUT[i] = act( sum_e w_e*H[src_e] + dis2[i]*H[i] + b ) ----------------

template <int F, bool RELU>
__global__ void aggregate_kernel(const float* __restrict__ H,
                                 const int* __restrict__ offsets,
                                 const int* __restrict__ csr_src,
                                 const float* __restrict__ csr_w,
                                 const float* __restrict__ dis,
                                 const float* __restrict__ bias,
                                 float* __restrict__ OUT)
{
    const int i = blockIdx.x;
    const int j = threadIdx.x;
    const float d = dis[i];
    float val = H[(size_t)i * F + j] * (d * d);
    const int e0 = offsets[i], e1 = offsets[i + 1];
    for (int e = e0; e < e1; ++e) {
        int s = csr_src[e];
        float w = csr_w[e];
        val = fmaf(w, H[(size_t)s * F + j], val);
    }
    val += bias[j];
    if (RELU) val = fmaxf(val, 0.f);
    OUT[(size_t)i * F + j] = val;
}

// ---------------- decode: logits[e] = dot(z[a], z[b]) over 128 dims ----------------

__global__ __launch_bounds__(256) void decode_kernel(const float* __restrict__ z,
                                                     const int* __restrict__ pos,
                                                     const int* __restrict__ neg,
                                                     float* __restrict__ out)
{
    const int wave = threadIdx.x >> 6;
    const int lane = threadIdx.x & 63;
    const int e = blockIdx.x * 4 + wave;
    if (e >= 2 * N_EVAL) return;
    int a, b;
    if (e < N_EVAL) { a = pos[e];          b = pos[N_EVAL + e]; }
    else            { a = neg[e - N_EVAL]; b = neg[e]; }  // neg[N_EVAL + (e - N_EVAL)] = neg[e]
    const float2 za = *(const float2*)(z + (size_t)a * 128 + lane * 2);
    const float2 zb = *(const float2*)(z + (size_t)b * 128 + lane * 2);
    float v = za.x * zb.x + za.y * zb.y;
#pragma unroll
    for (int d = 32; d > 0; d >>= 1) v += __shfl_xor(v, d);
    if (lane == 0) out[e] = v;
}

// ---------------- launch ----------------

extern "C" void kernel_launch(void* const* d_in, const int* in_sizes, int n_in,
                              void* d_out, int out_size, void* d_ws, size_t ws_size,
                              hipStream_t stream)
{
    const float* x  = (const float*)d_in[0];
    const int*   ei = (const int*)d_in[1];
    const int*  pos = (const int*)d_in[2];
    const int*  neg = (const int*)d_in[3];
    const float* W1 = (const float*)d_in[4];
    const float* b1 = (const float*)d_in[5];
    const float* W2 = (const float*)d_in[6];
    const float* b2 = (const float*)d_in[7];
    const float* W3 = (const float*)d_in[8];
    const float* b3 = (const float*)d_in[9];
    float* out = (float*)d_out;

    const int N = N_NODES, E = N_EDGES;

    char* p = (char*)d_ws;
    auto alloc = [&](size_t bytes) {
        char* r = p;
        p += (bytes + 255) & ~(size_t)255;
        return r;
    };
    int*   deg     = (int*)  alloc((size_t)N * 4);
    int*   offsets = (int*)  alloc((size_t)(N + 1) * 4);
    int*   cursor  = (int*)  alloc((size_t)N * 4);
    float* dis     = (float*)alloc((size_t)N * 4);
    int*   csrc    = (int*)  alloc((size_t)E * 4);
    float* cw      = (float*)alloc((size_t)E * 4);
    float* P       = (float*)alloc((size_t)N * 256 * 4);
    float* Q       = (float*)alloc((size_t)N * 256 * 4);

    const int* src = ei;
    const int* dst = ei + E;

    hipMemsetAsync(deg, 0, (size_t)N * 4, stream);
    count_deg_kernel<<<(E + 255) / 256, 256, 0, stream>>>(dst, deg, E);
    dis_kernel<<<(N + 255) / 256, 256, 0, stream>>>(deg, dis, N);
    scan_kernel<<<1, 1024, 0, stream>>>(deg, offsets, N, E);
    hipMemcpyAsync(cursor, offsets, (size_t)N * 4, hipMemcpyDeviceToDevice, stream);
    fill_csr_kernel<<<(E + 255) / 256, 256, 0, stream>>>(src, dst, dis, cursor, csrc, cw, E);

    // Layer 1: P = x @ W1 (K=128, N=256); Q = relu(aggr(P) + b1)
    dim3 g1((N + 127) / 128, 2);
    gemm_f32_kernel<<<g1, 256, 0, stream>>>(x, W1, P, N, 256, 128);
    aggregate_kernel<256, true><<<N, 256, 0, stream>>>(P, offsets, csrc, cw, dis, b1, Q);

    // Layer 2: P = Q @ W2 (K=256, N=256); Q = relu(aggr(P) + b2)
    gemm_f32_kernel<<<g1, 256, 0, stream>>>(Q, W2, P, N, 256, 256);
    aggregate_kernel<256, true><<<N, 256, 0, stream>>>(P, offsets, csrc, cw, dis, b2, Q);

    // Layer 3: P = Q @ W3 (K=256, N=128); Q = aggr(P) + b3  (no relu)
    dim3 g3((N + 127) / 128, 1);
    gemm_f32_kernel<<<g3, 256, 0, stream>>>(Q, W3, P, N, 128, 256);
    aggregate_kernel<128, false><<<N, 128, 0, stream>>>(P, offsets, csrc, cw, dis, b3, Q);

    // Decode
    decode_kernel<<<(2 * N_EVAL + 3) / 4, 256, 0, stream>>>(Q, pos, neg, out);
}

// Round 2
// 1258.438 us; speedup vs baseline: 1.2715x; 1.2715x over previous
//
#include <hip/hip_runtime.h>
#include <cstdint>
#include <cstddef>

#define N_NODES 100000
#define N_EDGES 1600000
#define N_EVAL  200000

// ---------------- degree / normalization ----------------

__global__ void count_deg_kernel(const int* __restrict__ dst, int* __restrict__ deg, int E) {
    int i = blockIdx.x * blockDim.x + threadIdx.x;
    if (i < E) atomicAdd(&deg[dst[i]], 1);
}

__global__ void dis_kernel(const int* __restrict__ deg, float* __restrict__ dis, int N) {
    int i = blockIdx.x * blockDim.x + threadIdx.x;
    if (i < N) dis[i] = rsqrtf((float)deg[i] + 1.0f);
}

// Single-block exclusive scan of deg -> offsets (N+1 entries).
__global__ __launch_bounds__(1024) void scan_kernel(const int* __restrict__ deg,
                                                    int* __restrict__ offsets, int N, int E) {
    __shared__ int sums[1024];
    int t = threadIdx.x;
    int C = (N + 1023) >> 10;
    int lo = t * C;
    int hi = min(lo + C, N);
    int s = 0;
    for (int i = lo; i < hi; ++i) s += deg[i];
    sums[t] = s;
    __syncthreads();
    for (int d = 1; d < 1024; d <<= 1) {
        int add = (t >= d) ? sums[t - d] : 0;
        __syncthreads();
        sums[t] += add;
        __syncthreads();
    }
    int run = sums[t] - s;           // exclusive prefix for this thread's chunk
    for (int i = lo; i < hi; ++i) { offsets[i] = run; run += deg[i]; }
    if (hi >= N) offsets[N] = E;
}

__global__ void fill_csr_kernel(const int* __restrict__ src, const int* __restrict__ dst,
                                const float* __restrict__ dis, int* __restrict__ cursor,
                                int* __restrict__ csr_src, float* __restrict__ csr_w, int E) {
    int e = blockIdx.x * blockDim.x + threadIdx.x;
    if (e < E) {
        int s = src[e], d = dst[e];
        int p = atomicAdd(&cursor[d], 1);
        csr_src[p] = s;
        csr_w[p] = dis[s] * dis[d];
    }
}

// ---------------- fp32 GEMM: C[M,N] = A[M,K] @ W[K,N] (+bias, relu) ----------------
// BM=128, BN=128, BK=16, 256 threads, 8x8 micro-tile per thread.

template <bool BIAS, bool RELU>
__global__ __launch_bounds__(256) void gemm_f32_kernel(
    const float* __restrict__ A, const float* __restrict__ W,
    float* __restrict__ C, int M, int N, int K, const float* __restrict__ bias)
{
    __shared__ float As[16][128];
    __shared__ float Ws[16][128];
    const int tid = threadIdx.x;
    const int m0 = blockIdx.x * 128;
    const int n0 = blockIdx.y * 128;
    const int ty = tid >> 4;         // 0..15
    const int tx = tid & 15;         // 0..15
    const int ar = tid >> 1;         // 0..127 (A row within tile)
    const int ak = (tid & 1) << 3;   // 0 or 8 (A k sub-offset)
    const int wr = tid >> 4;         // 0..15  (W row within k-tile)
    const int wc = (tid & 15) << 3;  // 0..120 (W col)

    float acc[8][8];
#pragma unroll
    for (int i = 0; i < 8; ++i)
#pragma unroll
        for (int j = 0; j < 8; ++j) acc[i][j] = 0.f;

    const int grow = m0 + ar;
    const float* Aptr = A + (size_t)grow * K + ak;
    const float* Wptr = W + (size_t)wr * N + n0 + wc;

    for (int k0 = 0; k0 < K; k0 += 16) {
        float4 a0, a1;
        if (grow < M) {
            a0 = *(const float4*)(Aptr + k0);
            a1 = *(const float4*)(Aptr + k0 + 4);
        } else {
            a0 = make_float4(0.f, 0.f, 0.f, 0.f);
            a1 = a0;
        }
        float4 w0 = *(const float4*)(Wptr + (size_t)k0 * N);
        float4 w1 = *(const float4*)(Wptr + (size_t)k0 * N + 4);
        As[ak + 0][ar] = a0.x; As[ak + 1][ar] = a0.y; As[ak + 2][ar] = a0.z; As[ak + 3][ar] = a0.w;
        As[ak + 4][ar] = a1.x; As[ak + 5][ar] = a1.y; As[ak + 6][ar] = a1.z; As[ak + 7][ar] = a1.w;
        *(float4*)&Ws[wr][wc]     = w0;
        *(float4*)&Ws[wr][wc + 4] = w1;
        __syncthreads();
#pragma unroll
        for (int kk = 0; kk < 16; ++kk) {
            float a[8], b[8];
            *(float4*)(a)     = *(const float4*)&As[kk][ty * 8];
            *(float4*)(a + 4) = *(const float4*)&As[kk][ty * 8 + 4];
            *(float4*)(b)     = *(const float4*)&Ws[kk][tx * 8];
            *(float4*)(b + 4) = *(const float4*)&Ws[kk][tx * 8 + 4];
#pragma unroll
            for (int i = 0; i < 8; ++i)
#pragma unroll
                for (int j = 0; j < 8; ++j)
                    acc[i][j] = fmaf(a[i], b[j], acc[i][j]);
        }
        __syncthreads();
    }

    float bb[8];
    if (BIAS) {
        *(float4*)(bb)     = *(const float4*)(bias + n0 + tx * 8);
        *(float4*)(bb + 4) = *(const float4*)(bias + n0 + tx * 8 + 4);
    }

#pragma unroll
    for (int i = 0; i < 8; ++i) {
        int row = m0 + ty * 8 + i;
        if (row < M) {
            float v[8];
#pragma unroll
            for (int j = 0; j < 8; ++j) {
                float t = acc[i][j];
                if (BIAS) t += bb[j];
                if (RELU) t = fmaxf(t, 0.f);
                v[j] = t;
            }
            float* cp = C + (size_t)row * N + n0 + tx * 8;
            *(float4*)(cp)     = *(const float4*)(v);
            *(float4*)(cp + 4) = *(const float4*)(v + 4);
        }
    }
}

// ---------------- aggregation (vectorized, one wave per node) ----------------
// OUT[i] = act( sum_e w_e*H[src_e] + dis[i]^2*H[i] (+ b) )

template <int VEC>
__device__ __forceinline__ void vload(float (&r)[VEC], const float* __restrict__ p) {
    if constexpr (VEC == 4) {
        float4 v = *(const float4*)p;
        r[0] = v.x; r[1] = v.y; r[2] = v.z; r[3] = v.w;
    } else {
        float2 v = *(const float2*)p;
        r[0] = v.x; r[1] = v.y;
    }
}

template <int F, bool BIAS, bool RELU>
__global__ __launch_bounds__(256) void aggregate_vec_kernel(
    const float* __restrict__ H,
    const int* __restrict__ offsets,
    const int* __restrict__ csr_src,
    const float* __restrict__ csr_w,
    const float* __restrict__ dis,
    const float* __restrict__ bias,
    float* __restrict__ OUT, int N)
{
    constexpr int VEC = F / 64;               // 4 for F=256, 2 for F=128
    const int node = blockIdx.x * 4 + (threadIdx.x >> 6);
    if (node >= N) return;
    const int lane = threadIdx.x & 63;
    const int col = lane * VEC;

    const float d = dis[node];
    float acc[VEC];
    {
        float v[VEC];
        vload<VEC>(v, H + (size_t)node * F + col);
        const float dd = d * d;
#pragma unroll
        for (int q = 0; q < VEC; ++q) acc[q] = v[q] * dd;
    }

    const int e0 = offsets[node], e1 = offsets[node + 1];
    int e = e0;
    for (; e + 2 <= e1; e += 2) {
        int s0 = csr_src[e], s1 = csr_src[e + 1];
        float w0 = csr_w[e], w1 = csr_w[e + 1];
        float v0[VEC], v1[VEC];
        vload<VEC>(v0, H + (size_t)s0 * F + col);
        vload<VEC>(v1, H + (size_t)s1 * F + col);
#pragma unroll
        for (int q = 0; q < VEC; ++q) acc[q] = fmaf(w0, v0[q], acc[q]);
#pragma unroll
        for (int q = 0; q < VEC; ++q) acc[q] = fmaf(w1, v1[q], acc[q]);
    }
    if (e < e1) {
        int s0 = csr_src[e];
        float w0 = csr_w[e];
        float v0[VEC];
        vload<VEC>(v0, H + (size_t)s0 * F + col);
#pragma unroll
        for (int q = 0; q < VEC; ++q) acc[q] = fmaf(w0, v0[q], acc[q]);
    }

    if (BIAS) {
        float b[VEC];
        vload<VEC>(b, bias + col);
#pragma unroll
        for (int q = 0; q < VEC; ++q) acc[q] += b[q];
    }
    if (RELU) {
#pragma unroll
        for (int q = 0; q < VEC; ++q) acc[q] = fmaxf(acc[q], 0.f);
    }

    float* op = OUT + (size_t)node * F + col;
    if constexpr (VEC == 4) {
        *(float4*)op = make_float4(acc[0], acc[1], acc[2], acc[3]);
    } else {
        *(float2*)op = make_float2(acc[0], acc[1]);
    }
}

// ---------------- decode: logits[e] = dot(z[a], z[b]) over 128 dims ----------------

__global__ __launch_bounds__(256) void decode_kernel(const float* __restrict__ z,
                                                     const int* __restrict__ pos,
                                                     const int* __restrict__ neg,
                                                     float* __restrict__ out)
{
    const int wave = threadIdx.x >> 6;
    const int lane = threadIdx.x & 63;
    const int e = blockIdx.x * 4 + wave;
    if (e >= 2 * N_EVAL) return;
    int a, b;
    if (e < N_EVAL) { a = pos[e];          b = pos[N_EVAL + e]; }
    else            { a = neg[e - N_EVAL]; b = neg[e]; }
    const float2 za = *(const float2*)(z + (size_t)a * 128 + lane * 2);
    const float2 zb = *(const float2*)(z + (size_t)b * 128 + lane * 2);
    float v = za.x * zb.x + za.y * zb.y;
#pragma unroll
    for (int d = 32; d > 0; d >>= 1) v += __shfl_xor(v, d);
    if (lane == 0) out[e] = v;
}

// ---------------- launch ----------------

extern "C" void kernel_launch(void* const* d_in, const int* in_sizes, int n_in,
                              void* d_out, int out_size, void* d_ws, size_t ws_size,
                              hipStream_t stream)
{
    const float* x  = (const float*)d_in[0];
    const int*   ei = (const int*)d_in[1];
    const int*  pos = (const int*)d_in[2];
    const int*  neg = (const int*)d_in[3];
    const float* W1 = (const float*)d_in[4];
    const float* b1 = (const float*)d_in[5];
    const float* W2 = (const float*)d_in[6];
    const float* b2 = (const float*)d_in[7];
    const float* W3 = (const float*)d_in[8];
    const float* b3 = (const float*)d_in[9];
    float* out = (float*)d_out;

    const int N = N_NODES, E = N_EDGES;

    char* p = (char*)d_ws;
    auto alloc = [&](size_t bytes) {
        char* r = p;
        p += (bytes + 255) & ~(size_t)255;
        return r;
    };
    int*   deg     = (int*)  alloc((size_t)N * 4);
    int*   offsets = (int*)  alloc((size_t)(N + 1) * 4);
    int*   cursor  = (int*)  alloc((size_t)N * 4);
    float* dis     = (float*)alloc((size_t)N * 4);
    int*   csrc    = (int*)  alloc((size_t)E * 4);
    float* cw      = (float*)alloc((size_t)E * 4);
    float* P       = (float*)alloc((size_t)N * 256 * 4);   // also holds XA=[N,128] for layer 1
    float* Q       = (float*)alloc((size_t)N * 256 * 4);

    const int* src = ei;
    const int* dst = ei + E;

    hipMemsetAsync(deg, 0, (size_t)N * 4, stream);
    count_deg_kernel<<<(E + 255) / 256, 256, 0, stream>>>(dst, deg, E);
    dis_kernel<<<(N + 255) / 256, 256, 0, stream>>>(deg, dis, N);
    scan_kernel<<<1, 1024, 0, stream>>>(deg, offsets, N, E);
    hipMemcpyAsync(cursor, offsets, (size_t)N * 4, hipMemcpyDeviceToDevice, stream);
    fill_csr_kernel<<<(E + 255) / 256, 256, 0, stream>>>(src, dst, dis, cursor, csrc, cw, E);

    const int agg_grid = (N + 3) / 4;

    // Layer 1 (reordered): XA = agg(x) [F=128]; Q = relu(XA @ W1 + b1)
    aggregate_vec_kernel<128, false, false><<<agg_grid, 256, 0, stream>>>(
        x, offsets, csrc, cw, dis, nullptr, P, N);
    dim3 g1((N + 127) / 128, 2);
    gemm_f32_kernel<true, true><<<g1, 256, 0, stream>>>(P, W1, Q, N, 256, 128, b1);

    // Layer 2: P = Q @ W2; Q = relu(agg(P) + b2)
    gemm_f32_kernel<false, false><<<g1, 256, 0, stream>>>(Q, W2, P, N, 256, 256, nullptr);
    aggregate_vec_kernel<256, true, true><<<agg_grid, 256, 0, stream>>>(
        P, offsets, csrc, cw, dis, b2, Q, N);

    // Layer 3: P = Q @ W3 (K=256, N=128); Q[:, :128] = agg(P) + b3
    dim3 g3((N + 127) / 128, 1);
    gemm_f32_kernel<false, false><<<g3, 256, 0, stream>>>(Q, W3, P, N, 128, 256, nullptr);
    float* Z = Q;  // reuse Q as [N,128]
    aggregate_vec_kernel<128, true, false><<<agg_grid, 256, 0, stream>>>(
        P, offsets, csrc, cw, dis, b3, Z, N);

    // Decode
    decode_kernel<<<(2 * N_EVAL + 3) / 4, 256, 0, stream>>>(Z, pos, neg, out);
}

// Round 3
// 1057.343 us; speedup vs baseline: 1.5133x; 1.1902x over previous
//
#include <hip/hip_runtime.h>
#include <cstdint>
#include <cstddef>

#define N_NODES 100000
#define N_EDGES 1600000
#define N_EVAL  200000

typedef __attribute__((ext_vector_type(8))) short bf16x8;
typedef __attribute__((ext_vector_type(4))) float f32x4;
typedef __attribute__((ext_vector_type(8))) unsigned short u16x8;

__device__ __forceinline__ unsigned short f2bf_rne(float f) {
    unsigned int u = __float_as_uint(f);
    unsigned int r = (u + 0x7FFFu + ((u >> 16) & 1u)) >> 16;
    return (unsigned short)r;
}
__device__ __forceinline__ float bf2f(unsigned short h) {
    return __uint_as_float(((unsigned int)h) << 16);
}

// ---------------- degree / normalization ----------------

__global__ void count_deg_kernel(const int* __restrict__ dst, int* __restrict__ deg, int E) {
    int i = blockIdx.x * blockDim.x + threadIdx.x;
    if (i < E) atomicAdd(&deg[dst[i]], 1);
}

__global__ void dis_kernel(const int* __restrict__ deg, float* __restrict__ dis, int N) {
    int i = blockIdx.x * blockDim.x + threadIdx.x;
    if (i < N) dis[i] = rsqrtf((float)deg[i] + 1.0f);
}

__global__ __launch_bounds__(1024) void scan_kernel(const int* __restrict__ deg,
                                                    int* __restrict__ offsets, int N, int E) {
    __shared__ int sums[1024];
    int t = threadIdx.x;
    int C = (N + 1023) >> 10;
    int lo = t * C;
    int hi = min(lo + C, N);
    int s = 0;
    for (int i = lo; i < hi; ++i) s += deg[i];
    sums[t] = s;
    __syncthreads();
    for (int d = 1; d < 1024; d <<= 1) {
        int add = (t >= d) ? sums[t - d] : 0;
        __syncthreads();
        sums[t] += add;
        __syncthreads();
    }
    int run = sums[t] - s;
    for (int i = lo; i < hi; ++i) { offsets[i] = run; run += deg[i]; }
    if (hi >= N) offsets[N] = E;
}

__global__ void fill_csr_kernel(const int* __restrict__ src, const int* __restrict__ dst,
                                const float* __restrict__ dis, int* __restrict__ cursor,
                                int* __restrict__ csr_src, float* __restrict__ csr_w, int E) {
    int e = blockIdx.x * blockDim.x + threadIdx.x;
    if (e < E) {
        int s = src[e], d = dst[e];
        int p = atomicAdd(&cursor[d], 1);
        csr_src[p] = s;
        csr_w[p] = dis[s] * dis[d];
    }
}

// ---------------- W transpose + bf16 hi/lo split: W[K][N] -> Wt_hi/lo[N][K] ----------------

__global__ void wsplit_kernel(const float* __restrict__ W, unsigned short* __restrict__ Wt_hi,
                              unsigned short* __restrict__ Wt_lo, int K, int N) {
    int idx = blockIdx.x * blockDim.x + threadIdx.x;
    if (idx >= K * N) return;
    int k = idx / N, n = idx - k * N;
    float v = W[idx];
    unsigned short h = f2bf_rne(v);
    Wt_hi[(size_t)n * K + k] = h;
    Wt_lo[(size_t)n * K + k] = f2bf_rne(v - bf2f(h));
}

// ---------------- split-bf16 MFMA GEMM: C[M,N] = A[M,K] @ W[K,N] (+bias,relu) ----------------
// A fp32 row-major (converted to hi/lo bf16 during staging); W pre-split as Wt_hi/lo [N][K].
// BM=BN=128, BK=32, 256 threads (4 waves as 2x2 of 64x64), 16x16x32 bf16 MFMA, 3 products.

#define KP 40   // padded LDS row (bf16): 80B rows -> 16B-aligned, ~2-way-conflict frag reads

template <bool BIAS, bool RELU>
__global__ __launch_bounds__(256, 2) void gemm_bf16split_kernel(
    const float* __restrict__ A,
    const unsigned short* __restrict__ Wt_hi,
    const unsigned short* __restrict__ Wt_lo,
    float* __restrict__ C, int M, int N, int K,
    const float* __restrict__ bias)
{
    __shared__ unsigned short As_hi[128][KP];
    __shared__ unsigned short As_lo[128][KP];
    __shared__ unsigned short Bs_hi[128][KP];
    __shared__ unsigned short Bs_lo[128][KP];

    const int tid = threadIdx.x;
    const int m0 = blockIdx.x * 128;
    const int n0 = blockIdx.y * 128;
    const int lane = tid & 63;
    const int wave = tid >> 6;
    const int wm0 = (wave >> 1) * 64;
    const int wn0 = (wave & 1) * 64;
    const int fr = lane & 15;          // fragment row index (m or n within 16)
    const int fk = (lane >> 4) * 8;    // fragment k offset

    f32x4 acc[4][4];
#pragma unroll
    for (int i = 0; i < 4; ++i)
#pragma unroll
        for (int j = 0; j < 4; ++j) acc[i][j] = (f32x4){0.f, 0.f, 0.f, 0.f};

    const int srow = tid >> 1;             // 0..127
    const int sc0 = (tid & 1) * 16;        // 0 or 16
    const int agrow = m0 + srow;
    const float* Ap = A + (size_t)agrow * K + sc0;
    const unsigned short* Bh = Wt_hi + (size_t)(n0 + srow) * K + sc0;
    const unsigned short* Bl = Wt_lo + (size_t)(n0 + srow) * K + sc0;

    for (int k0 = 0; k0 < K; k0 += 32) {
        // ---- stage A (fp32 -> hi/lo bf16) ----
        float a[16];
        if (agrow < M) {
            *(float4*)(a)      = *(const float4*)(Ap + k0);
            *(float4*)(a + 4)  = *(const float4*)(Ap + k0 + 4);
            *(float4*)(a + 8)  = *(const float4*)(Ap + k0 + 8);
            *(float4*)(a + 12) = *(const float4*)(Ap + k0 + 12);
        } else {
#pragma unroll
            for (int i = 0; i < 16; ++i) a[i] = 0.f;
        }
        unsigned short h[16], l[16];
#pragma unroll
        for (int i = 0; i < 16; ++i) {
            unsigned short hh = f2bf_rne(a[i]);
            h[i] = hh;
            l[i] = f2bf_rne(a[i] - bf2f(hh));
        }
        *(u16x8*)&As_hi[srow][sc0]     = *(const u16x8*)(h);
        *(u16x8*)&As_hi[srow][sc0 + 8] = *(const u16x8*)(h + 8);
        *(u16x8*)&As_lo[srow][sc0]     = *(const u16x8*)(l);
        *(u16x8*)&As_lo[srow][sc0 + 8] = *(const u16x8*)(l + 8);
        // ---- stage B (already bf16, already [n][k]) ----
        *(u16x8*)&Bs_hi[srow][sc0]     = *(const u16x8*)(Bh + k0);
        *(u16x8*)&Bs_hi[srow][sc0 + 8] = *(const u16x8*)(Bh + k0 + 8);
        *(u16x8*)&Bs_lo[srow][sc0]     = *(const u16x8*)(Bl + k0);
        *(u16x8*)&Bs_lo[srow][sc0 + 8] = *(const u16x8*)(Bl + k0 + 8);
        __syncthreads();

        bf16x8 af_h[4], af_l[4], bf_h[4], bf_l[4];
#pragma unroll
        for (int i = 0; i < 4; ++i) {
            af_h[i] = *(const bf16x8*)&As_hi[wm0 + i * 16 + fr][fk];
            af_l[i] = *(const bf16x8*)&As_lo[wm0 + i * 16 + fr][fk];
            bf_h[i] = *(const bf16x8*)&Bs_hi[wn0 + i * 16 + fr][fk];
            bf_l[i] = *(const bf16x8*)&Bs_lo[wn0 + i * 16 + fr][fk];
        }
#pragma unroll
        for (int i = 0; i < 4; ++i)
#pragma unroll
            for (int j = 0; j < 4; ++j) {
                acc[i][j] = __builtin_amdgcn_mfma_f32_16x16x32_bf16(af_h[i], bf_h[j], acc[i][j], 0, 0, 0);
                acc[i][j] = __builtin_amdgcn_mfma_f32_16x16x32_bf16(af_l[i], bf_h[j], acc[i][j], 0, 0, 0);
                acc[i][j] = __builtin_amdgcn_mfma_f32_16x16x32_bf16(af_h[i], bf_l[j], acc[i][j], 0, 0, 0);
            }
        __syncthreads();
    }

    // ---- epilogue: C = acc (+bias, relu). D layout: col=lane&15, row=(lane>>4)*4+r ----
#pragma unroll
    for (int j = 0; j < 4; ++j) {
        const int col = n0 + wn0 + j * 16 + fr;
        const float bb = BIAS ? bias[col] : 0.f;
#pragma unroll
        for (int i = 0; i < 4; ++i) {
            const int rbase = m0 + wm0 + i * 16 + (lane >> 4) * 4;
#pragma unroll
            for (int r = 0; r < 4; ++r) {
                const int row = rbase + r;
                if (row < M) {
                    float v = acc[i][j][r] + bb;
                    if (RELU) v = fmaxf(v, 0.f);
                    C[(size_t)row * N + col] = v;
                }
            }
        }
    }
}

// ---------------- aggregation (vectorized, one wave per node, 4x unroll) ----------------

template <int VEC>
__device__ __forceinline__ void vload(float (&r)[VEC], const float* __restrict__ p) {
    if constexpr (VEC == 4) {
        float4 v = *(const float4*)p;
        r[0] = v.x; r[1] = v.y; r[2] = v.z; r[3] = v.w;
    } else {
        float2 v = *(const float2*)p;
        r[0] = v.x; r[1] = v.y;
    }
}

template <int F, bool BIAS, bool RELU>
__global__ __launch_bounds__(256) void aggregate_vec_kernel(
    const float* __restrict__ H,
    const int* __restrict__ offsets,
    const int* __restrict__ csr_src,
    const float* __restrict__ csr_w,
    const float* __restrict__ dis,
    const float* __restrict__ bias,
    float* __restrict__ OUT, int N)
{
    constexpr int VEC = F / 64;
    const int node = blockIdx.x * 4 + (threadIdx.x >> 6);
    if (node >= N) return;
    const int lane = threadIdx.x & 63;
    const int col = lane * VEC;

    const float d = dis[node];
    float acc[VEC];
    {
        float v[VEC];
        vload<VEC>(v, H + (size_t)node * F + col);
        const float dd = d * d;
#pragma unroll
        for (int q = 0; q < VEC; ++q) acc[q] = v[q] * dd;
    }

    const int e0 = offsets[node], e1 = offsets[node + 1];
    int e = e0;
    for (; e + 4 <= e1; e += 4) {
        int s0 = csr_src[e], s1 = csr_src[e + 1], s2 = csr_src[e + 2], s3 = csr_src[e + 3];
        float w0 = csr_w[e], w1 = csr_w[e + 1], w2 = csr_w[e + 2], w3 = csr_w[e + 3];
        float v0[VEC], v1[VEC], v2[VEC], v3[VEC];
        vload<VEC>(v0, H + (size_t)s0 * F + col);
        vload<VEC>(v1, H + (size_t)s1 * F + col);
        vload<VEC>(v2, H + (size_t)s2 * F + col);
        vload<VEC>(v3, H + (size_t)s3 * F + col);
#pragma unroll
        for (int q = 0; q < VEC; ++q) acc[q] = fmaf(w0, v0[q], acc[q]);
#pragma unroll
        for (int q = 0; q < VEC; ++q) acc[q] = fmaf(w1, v1[q], acc[q]);
#pragma unroll
        for (int q = 0; q < VEC; ++q) acc[q] = fmaf(w2, v2[q], acc[q]);
#pragma unroll
        for (int q = 0; q < VEC; ++q) acc[q] = fmaf(w3, v3[q], acc[q]);
    }
    for (; e < e1; ++e) {
        int s0 = csr_src[e];
        float w0 = csr_w[e];
        float v0[VEC];
        vload<VEC>(v0, H + (size_t)s0 * F + col);
#pragma unroll
        for (int q = 0; q < VEC; ++q) acc[q] = fmaf(w0, v0[q], acc[q]);
    }

    if (BIAS) {
        float b[VEC];
        vload<VEC>(b, bias + col);
#pragma unroll
        for (int q = 0; q < VEC; ++q) acc[q] += b[q];
    }
    if (RELU) {
#pragma unroll
        for (int q = 0; q < VEC; ++q) acc[q] = fmaxf(acc[q], 0.f);
    }

    float* op = OUT + (size_t)node * F + col;
    if constexpr (VEC == 4) {
        *(float4*)op = make_float4(acc[0], acc[1], acc[2], acc[3]);
    } else {
        *(float2*)op = make_float2(acc[0], acc[1]);
    }
}

// ---------------- decode ----------------

__global__ __launch_bounds__(256) void decode_kernel(const float* __restrict__ z,
                                                     const int* __restrict__ pos,
                                                     const int* __restrict__ neg,
                                                     float* __restrict__ out)
{
    const int wave = threadIdx.x >> 6;
    const int lane = threadIdx.x & 63;
    const int e = blockIdx.x * 4 + wave;
    if (e >= 2 * N_EVAL) return;
    int a, b;
    if (e < N_EVAL) { a = pos[e];          b = pos[N_EVAL + e]; }
    else            { a = neg[e - N_EVAL]; b = neg[e]; }
    const float2 za = *(const float2*)(z + (size_t)a * 128 + lane * 2);
    const float2 zb = *(const float2*)(z + (size_t)b * 128 + lane * 2);
    float v = za.x * zb.x + za.y * zb.y;
#pragma unroll
    for (int d = 32; d > 0; d >>= 1) v += __shfl_xor(v, d);
    if (lane == 0) out[e] = v;
}

// ---------------- launch ----------------

extern "C" void kernel_launch(void* const* d_in, const int* in_sizes, int n_in,
                              void* d_out, int out_size, void* d_ws, size_t ws_size,
                              hipStream_t stream)
{
    const float* x  = (const float*)d_in[0];
    const int*   ei = (const int*)d_in[1];
    const int*  pos = (const int*)d_in[2];
    const int*  neg = (const int*)d_in[3];
    const float* W1 = (const float*)d_in[4];
    const float* b1 = (const float*)d_in[5];
    const float* W2 = (const float*)d_in[6];
    const float* b2 = (const float*)d_in[7];
    const float* W3 = (const float*)d_in[8];
    const float* b3 = (const float*)d_in[9];
    float* out = (float*)d_out;

    const int N = N_NODES, E = N_EDGES;

    char* p = (char*)d_ws;
    auto alloc = [&](size_t bytes) {
        char* r = p;
        p += (bytes + 255) & ~(size_t)255;
        return r;
    };
    int*   deg     = (int*)  alloc((size_t)N * 4);
    int*   offsets = (int*)  alloc((size_t)(N + 1) * 4);
    int*   cursor  = (int*)  alloc((size_t)N * 4);
    float* dis     = (float*)alloc((size_t)N * 4);
    int*   csrc    = (int*)  alloc((size_t)E * 4);
    float* cw      = (float*)alloc((size_t)E * 4);
    float* P       = (float*)alloc((size_t)N * 256 * 4);
    float* Q       = (float*)alloc((size_t)N * 256 * 4);
    unsigned short* W1h = (unsigned short*)alloc((size_t)256 * 128 * 2);
    unsigned short* W1l = (unsigned short*)alloc((size_t)256 * 128 * 2);
    unsigned short* W2h = (unsigned short*)alloc((size_t)256 * 256 * 2);
    unsigned short* W2l = (unsigned short*)alloc((size_t)256 * 256 * 2);
    unsigned short* W3h = (unsigned short*)alloc((size_t)128 * 256 * 2);
    unsigned short* W3l = (unsigned short*)alloc((size_t)128 * 256 * 2);

    const int* src = ei;
    const int* dst = ei + E;

    // W preprocessing (independent of graph work)
    wsplit_kernel<<<(128 * 256 + 255) / 256, 256, 0, stream>>>(W1, W1h, W1l, 128, 256);
    wsplit_kernel<<<(256 * 256 + 255) / 256, 256, 0, stream>>>(W2, W2h, W2l, 256, 256);
    wsplit_kernel<<<(256 * 128 + 255) / 256, 256, 0, stream>>>(W3, W3h, W3l, 256, 128);

    hipMemsetAsync(deg, 0, (size_t)N * 4, stream);
    count_deg_kernel<<<(E + 255) / 256, 256, 0, stream>>>(dst, deg, E);
    dis_kernel<<<(N + 255) / 256, 256, 0, stream>>>(deg, dis, N);
    scan_kernel<<<1, 1024, 0, stream>>>(deg, offsets, N, E);
    hipMemcpyAsync(cursor, offsets, (size_t)N * 4, hipMemcpyDeviceToDevice, stream);
    fill_csr_kernel<<<(E + 255) / 256, 256, 0, stream>>>(src, dst, dis, cursor, csrc, cw, E);

    const int agg_grid = (N + 3) / 4;
    const int mblocks = (N + 127) / 128;

    // Layer 1: P = agg(x) [F=128]; Q = relu(P @ W1 + b1)
    aggregate_vec_kernel<128, false, false><<<agg_grid, 256, 0, stream>>>(
        x, offsets, csrc, cw, dis, nullptr, P, N);
    gemm_bf16split_kernel<true, true><<<dim3(mblocks, 2), 256, 0, stream>>>(
        P, W1h, W1l, Q, N, 256, 128, b1);

    // Layer 2: P = Q @ W2; Q = relu(agg(P) + b2)
    gemm_bf16split_kernel<false, false><<<dim3(mblocks, 2), 256, 0, stream>>>(
        Q, W2h, W2l, P, N, 256, 256, nullptr);
    aggregate_vec_kernel<256, true, true><<<agg_grid, 256, 0, stream>>>(
        P, offsets, csrc, cw, dis, b2, Q, N);

    // Layer 3: P = Q @ W3 [N=128]; Z = agg(P) + b3
    gemm_bf16split_kernel<false, false><<<dim3(mblocks, 1), 256, 0, stream>>>(
        Q, W3h, W3l, P, N, 128, 256, nullptr);
    float* Z = Q;
    aggregate_vec_kernel<128, true, false><<<agg_grid, 256, 0, stream>>>(
        P, offsets, csrc, cw, dis, b3, Z, N);

    // Decode
    decode_kernel<<<(2 * N_EVAL + 3) / 4, 256, 0, stream>>>(Z, pos, neg, out);
}

// Round 4
// 1004.733 us; speedup vs baseline: 1.5925x; 1.0524x over previous
//
#include <hip/hip_runtime.h>
#include <cstdint>
#include <cstddef>

#define N_NODES 100000
#define N_EDGES 1600000
#define N_EVAL  200000

typedef __attribute__((ext_vector_type(8))) short bf16x8;
typedef __attribute__((ext_vector_type(4))) float f32x4;
typedef __attribute__((ext_vector_type(8))) unsigned short u16x8;

__device__ __forceinline__ unsigned short f2bf_rne(float f) {
    unsigned int u = __float_as_uint(f);
    unsigned int r = (u + 0x7FFFu + ((u >> 16) & 1u)) >> 16;
    return (unsigned short)r;
}
__device__ __forceinline__ float bf2f(unsigned short h) {
    return __uint_as_float(((unsigned int)h) << 16);
}

// ---------------- degree / normalization ----------------

__global__ void count_deg_kernel(const int* __restrict__ dst, int* __restrict__ deg, int E) {
    int i = blockIdx.x * blockDim.x + threadIdx.x;
    if (i < E) atomicAdd(&deg[dst[i]], 1);
}

__global__ void dis_kernel(const int* __restrict__ deg, float* __restrict__ dis, int N) {
    int i = blockIdx.x * blockDim.x + threadIdx.x;
    if (i < N) dis[i] = rsqrtf((float)deg[i] + 1.0f);
}

__global__ __launch_bounds__(1024) void scan_kernel(const int* __restrict__ deg,
                                                    int* __restrict__ offsets, int N, int E) {
    __shared__ int sums[1024];
    int t = threadIdx.x;
    int C = (N + 1023) >> 10;
    int lo = t * C;
    int hi = min(lo + C, N);
    int s = 0;
    for (int i = lo; i < hi; ++i) s += deg[i];
    sums[t] = s;
    __syncthreads();
    for (int d = 1; d < 1024; d <<= 1) {
        int add = (t >= d) ? sums[t - d] : 0;
        __syncthreads();
        sums[t] += add;
        __syncthreads();
    }
    int run = sums[t] - s;
    for (int i = lo; i < hi; ++i) { offsets[i] = run; run += deg[i]; }
    if (hi >= N) offsets[N] = E;
}

// CSR entry packed: .x = src index, .y = bit pattern of weight
__global__ void fill_csr_kernel(const int* __restrict__ src, const int* __restrict__ dst,
                                const float* __restrict__ dis, int* __restrict__ cursor,
                                int2* __restrict__ csr, int E) {
    int e = blockIdx.x * blockDim.x + threadIdx.x;
    if (e < E) {
        int s = src[e], d = dst[e];
        int p = atomicAdd(&cursor[d], 1);
        csr[p] = make_int2(s, __float_as_int(dis[s] * dis[d]));
    }
}

// ---------------- W transpose + bf16 hi/lo split: W[K][N] -> Wt_hi/lo[N][K] ----------------

__global__ void wsplit_kernel(const float* __restrict__ W, unsigned short* __restrict__ Wt_hi,
                              unsigned short* __restrict__ Wt_lo, int K, int N) {
    int idx = blockIdx.x * blockDim.x + threadIdx.x;
    if (idx >= K * N) return;
    int k = idx / N, n = idx - k * N;
    float v = W[idx];
    unsigned short h = f2bf_rne(v);
    Wt_hi[(size_t)n * K + k] = h;
    Wt_lo[(size_t)n * K + k] = f2bf_rne(v - bf2f(h));
}

// ---------------- split-bf16 MFMA GEMM ----------------

#define KP 40

template <bool BIAS, bool RELU>
__global__ __launch_bounds__(256, 2) void gemm_bf16split_kernel(
    const float* __restrict__ A,
    const unsigned short* __restrict__ Wt_hi,
    const unsigned short* __restrict__ Wt_lo,
    float* __restrict__ C, int M, int N, int K,
    const float* __restrict__ bias)
{
    __shared__ unsigned short As_hi[128][KP];
    __shared__ unsigned short As_lo[128][KP];
    __shared__ unsigned short Bs_hi[128][KP];
    __shared__ unsigned short Bs_lo[128][KP];

    const int tid = threadIdx.x;
    const int m0 = blockIdx.x * 128;
    const int n0 = blockIdx.y * 128;
    const int lane = tid & 63;
    const int wave = tid >> 6;
    const int wm0 = (wave >> 1) * 64;
    const int wn0 = (wave & 1) * 64;
    const int fr = lane & 15;
    const int fk = (lane >> 4) * 8;

    f32x4 acc[4][4];
#pragma unroll
    for (int i = 0; i < 4; ++i)
#pragma unroll
        for (int j = 0; j < 4; ++j) acc[i][j] = (f32x4){0.f, 0.f, 0.f, 0.f};

    const int srow = tid >> 1;
    const int sc0 = (tid & 1) * 16;
    const int agrow = m0 + srow;
    const float* Ap = A + (size_t)agrow * K + sc0;
    const unsigned short* Bh = Wt_hi + (size_t)(n0 + srow) * K + sc0;
    const unsigned short* Bl = Wt_lo + (size_t)(n0 + srow) * K + sc0;

    for (int k0 = 0; k0 < K; k0 += 32) {
        float a[16];
        if (agrow < M) {
            *(float4*)(a)      = *(const float4*)(Ap + k0);
            *(float4*)(a + 4)  = *(const float4*)(Ap + k0 + 4);
            *(float4*)(a + 8)  = *(const float4*)(Ap + k0 + 8);
            *(float4*)(a + 12) = *(const float4*)(Ap + k0 + 12);
        } else {
#pragma unroll
            for (int i = 0; i < 16; ++i) a[i] = 0.f;
        }
        unsigned short h[16], l[16];
#pragma unroll
        for (int i = 0; i < 16; ++i) {
            unsigned short hh = f2bf_rne(a[i]);
            h[i] = hh;
            l[i] = f2bf_rne(a[i] - bf2f(hh));
        }
        *(u16x8*)&As_hi[srow][sc0]     = *(const u16x8*)(h);
        *(u16x8*)&As_hi[srow][sc0 + 8] = *(const u16x8*)(h + 8);
        *(u16x8*)&As_lo[srow][sc0]     = *(const u16x8*)(l);
        *(u16x8*)&As_lo[srow][sc0 + 8] = *(const u16x8*)(l + 8);
        *(u16x8*)&Bs_hi[srow][sc0]     = *(const u16x8*)(Bh + k0);
        *(u16x8*)&Bs_hi[srow][sc0 + 8] = *(const u16x8*)(Bh + k0 + 8);
        *(u16x8*)&Bs_lo[srow][sc0]     = *(const u16x8*)(Bl + k0);
        *(u16x8*)&Bs_lo[srow][sc0 + 8] = *(const u16x8*)(Bl + k0 + 8);
        __syncthreads();

        bf16x8 af_h[4], af_l[4], bf_h[4], bf_l[4];
#pragma unroll
        for (int i = 0; i < 4; ++i) {
            af_h[i] = *(const bf16x8*)&As_hi[wm0 + i * 16 + fr][fk];
            af_l[i] = *(const bf16x8*)&As_lo[wm0 + i * 16 + fr][fk];
            bf_h[i] = *(const bf16x8*)&Bs_hi[wn0 + i * 16 + fr][fk];
            bf_l[i] = *(const bf16x8*)&Bs_lo[wn0 + i * 16 + fr][fk];
        }
#pragma unroll
        for (int i = 0; i < 4; ++i)
#pragma unroll
            for (int j = 0; j < 4; ++j) {
                acc[i][j] = __builtin_amdgcn_mfma_f32_16x16x32_bf16(af_h[i], bf_h[j], acc[i][j], 0, 0, 0);
                acc[i][j] = __builtin_amdgcn_mfma_f32_16x16x32_bf16(af_l[i], bf_h[j], acc[i][j], 0, 0, 0);
                acc[i][j] = __builtin_amdgcn_mfma_f32_16x16x32_bf16(af_h[i], bf_l[j], acc[i][j], 0, 0, 0);
            }
        __syncthreads();
    }

#pragma unroll
    for (int j = 0; j < 4; ++j) {
        const int col = n0 + wn0 + j * 16 + fr;
        const float bb = BIAS ? bias[col] : 0.f;
#pragma unroll
        for (int i = 0; i < 4; ++i) {
            const int rbase = m0 + wm0 + i * 16 + (lane >> 4) * 4;
#pragma unroll
            for (int r = 0; r < 4; ++r) {
                const int row = rbase + r;
                if (row < M) {
                    float v = acc[i][j][r] + bb;
                    if (RELU) v = fmaxf(v, 0.f);
                    C[(size_t)row * N + col] = v;
                }
            }
        }
    }
}

// ---------------- aggregation (one wave per node, 8x edge unroll) ----------------

template <int VEC>
__device__ __forceinline__ void vload(float (&r)[VEC], const float* __restrict__ p) {
    if constexpr (VEC == 4) {
        float4 v = *(const float4*)p;
        r[0] = v.x; r[1] = v.y; r[2] = v.z; r[3] = v.w;
    } else {
        float2 v = *(const float2*)p;
        r[0] = v.x; r[1] = v.y;
    }
}

template <int F, bool BIAS, bool RELU>
__global__ __launch_bounds__(256) void aggregate_vec_kernel(
    const float* __restrict__ H,
    const int* __restrict__ offsets,
    const int2* __restrict__ csr,
    const float* __restrict__ dis,
    const float* __restrict__ bias,
    float* __restrict__ OUT, int N)
{
    constexpr int VEC = F / 64;
    const int node = blockIdx.x * 4 + (threadIdx.x >> 6);
    if (node >= N) return;
    const int lane = threadIdx.x & 63;
    const int col = lane * VEC;

    const float d = dis[node];
    float acc[VEC];
    {
        float v[VEC];
        vload<VEC>(v, H + (size_t)node * F + col);
        const float dd = d * d;
#pragma unroll
        for (int q = 0; q < VEC; ++q) acc[q] = v[q] * dd;
    }

    const int e0 = offsets[node], e1 = offsets[node + 1];
    int e = e0;
    for (; e + 8 <= e1; e += 8) {
        int2 c[8];
#pragma unroll
        for (int q = 0; q < 8; ++q) c[q] = csr[e + q];
        float v[8][VEC];
#pragma unroll
        for (int q = 0; q < 8; ++q) vload<VEC>(v[q], H + (size_t)c[q].x * F + col);
#pragma unroll
        for (int q = 0; q < 8; ++q) {
            const float w = __int_as_float(c[q].y);
#pragma unroll
            for (int vv = 0; vv < VEC; ++vv) acc[vv] = fmaf(w, v[q][vv], acc[vv]);
        }
    }
    for (; e + 2 <= e1; e += 2) {
        int2 c0 = csr[e], c1 = csr[e + 1];
        float v0[VEC], v1[VEC];
        vload<VEC>(v0, H + (size_t)c0.x * F + col);
        vload<VEC>(v1, H + (size_t)c1.x * F + col);
        const float w0 = __int_as_float(c0.y), w1 = __int_as_float(c1.y);
#pragma unroll
        for (int q = 0; q < VEC; ++q) acc[q] = fmaf(w0, v0[q], acc[q]);
#pragma unroll
        for (int q = 0; q < VEC; ++q) acc[q] = fmaf(w1, v1[q], acc[q]);
    }
    if (e < e1) {
        int2 c0 = csr[e];
        float v0[VEC];
        vload<VEC>(v0, H + (size_t)c0.x * F + col);
        const float w0 = __int_as_float(c0.y);
#pragma unroll
        for (int q = 0; q < VEC; ++q) acc[q] = fmaf(w0, v0[q], acc[q]);
    }

    if (BIAS) {
        float b[VEC];
        vload<VEC>(b, bias + col);
#pragma unroll
        for (int q = 0; q < VEC; ++q) acc[q] += b[q];
    }
    if (RELU) {
#pragma unroll
        for (int q = 0; q < VEC; ++q) acc[q] = fmaxf(acc[q], 0.f);
    }

    float* op = OUT + (size_t)node * F + col;
    if constexpr (VEC == 4) {
        *(float4*)op = make_float4(acc[0], acc[1], acc[2], acc[3]);
    } else {
        *(float2*)op = make_float2(acc[0], acc[1]);
    }
}

// ---------------- decode: 4 edges per wave, unrolled ----------------

__global__ __launch_bounds__(256) void decode_kernel(const float* __restrict__ z,
                                                     const int* __restrict__ pos,
                                                     const int* __restrict__ neg,
                                                     float* __restrict__ out)
{
    const int wave = threadIdx.x >> 6;
    const int lane = threadIdx.x & 63;
    const int ebase = (blockIdx.x * 4 + wave) * 4;
    if (ebase >= 2 * N_EVAL) return;
    int ia[4], ib[4];
#pragma unroll
    for (int q = 0; q < 4; ++q) {
        const int e = ebase + q;
        if (e < N_EVAL) { ia[q] = pos[e];          ib[q] = pos[N_EVAL + e]; }
        else            { ia[q] = neg[e - N_EVAL]; ib[q] = neg[e]; }
    }
    float2 za[4], zb[4];
#pragma unroll
    for (int q = 0; q < 4; ++q) {
        za[q] = *(const float2*)(z + (size_t)ia[q] * 128 + lane * 2);
        zb[q] = *(const float2*)(z + (size_t)ib[q] * 128 + lane * 2);
    }
    float v[4];
#pragma unroll
    for (int q = 0; q < 4; ++q) v[q] = za[q].x * zb[q].x + za[q].y * zb[q].y;
#pragma unroll
    for (int d = 32; d > 0; d >>= 1) {
#pragma unroll
        for (int q = 0; q < 4; ++q) v[q] += __shfl_xor(v[q], d);
    }
    if (lane == 0) {
#pragma unroll
        for (int q = 0; q < 4; ++q) out[ebase + q] = v[q];
    }
}

// ---------------- launch ----------------

extern "C" void kernel_launch(void* const* d_in, const int* in_sizes, int n_in,
                              void* d_out, int out_size, void* d_ws, size_t ws_size,
                              hipStream_t stream)
{
    const float* x  = (const float*)d_in[0];
    const int*   ei = (const int*)d_in[1];
    const int*  pos = (const int*)d_in[2];
    const int*  neg = (const int*)d_in[3];
    const float* W1 = (const float*)d_in[4];
    const float* b1 = (const float*)d_in[5];
    const float* W2 = (const float*)d_in[6];
    const float* b2 = (const float*)d_in[7];
    const float* W3 = (const float*)d_in[8];
    const float* b3 = (const float*)d_in[9];
    float* out = (float*)d_out;

    const int N = N_NODES, E = N_EDGES;

    char* p = (char*)d_ws;
    auto alloc = [&](size_t bytes) {
        char* r = p;
        p += (bytes + 255) & ~(size_t)255;
        return r;
    };
    int*   deg     = (int*)  alloc((size_t)N * 4);
    int*   offsets = (int*)  alloc((size_t)(N + 1) * 4);
    int*   cursor  = (int*)  alloc((size_t)N * 4);
    float* dis     = (float*)alloc((size_t)N * 4);
    int2*  csr     = (int2*) alloc((size_t)E * 8);
    float* P       = (float*)alloc((size_t)N * 256 * 4);
    float* Q       = (float*)alloc((size_t)N * 256 * 4);
    unsigned short* W1h = (unsigned short*)alloc((size_t)256 * 128 * 2);
    unsigned short* W1l = (unsigned short*)alloc((size_t)256 * 128 * 2);
    unsigned short* W2h = (unsigned short*)alloc((size_t)256 * 256 * 2);
    unsigned short* W2l = (unsigned short*)alloc((size_t)256 * 256 * 2);
    unsigned short* W3h = (unsigned short*)alloc((size_t)128 * 256 * 2);
    unsigned short* W3l = (unsigned short*)alloc((size_t)128 * 256 * 2);

    const int* src = ei;
    const int* dst = ei + E;

    wsplit_kernel<<<(128 * 256 + 255) / 256, 256, 0, stream>>>(W1, W1h, W1l, 128, 256);
    wsplit_kernel<<<(256 * 256 + 255) / 256, 256, 0, stream>>>(W2, W2h, W2l, 256, 256);
    wsplit_kernel<<<(256 * 128 + 255) / 256, 256, 0, stream>>>(W3, W3h, W3l, 256, 128);

    hipMemsetAsync(deg, 0, (size_t)N * 4, stream);
    count_deg_kernel<<<(E + 255) / 256, 256, 0, stream>>>(dst, deg, E);
    dis_kernel<<<(N + 255) / 256, 256, 0, stream>>>(deg, dis, N);
    scan_kernel<<<1, 1024, 0, stream>>>(deg, offsets, N, E);
    hipMemcpyAsync(cursor, offsets, (size_t)N * 4, hipMemcpyDeviceToDevice, stream);
    fill_csr_kernel<<<(E + 255) / 256, 256, 0, stream>>>(src, dst, dis, cursor, csr, E);

    const int agg_grid = (N + 3) / 4;
    const int mblocks = (N + 127) / 128;

    // Layer 1: P = agg(x) [F=128]; Q = relu(P @ W1 + b1)
    aggregate_vec_kernel<128, false, false><<<agg_grid, 256, 0, stream>>>(
        x, offsets, csr, dis, nullptr, P, N);
    gemm_bf16split_kernel<true, true><<<dim3(mblocks, 2), 256, 0, stream>>>(
        P, W1h, W1l, Q, N, 256, 128, b1);

    // Layer 2: P = Q @ W2; Q = relu(agg(P) + b2)
    gemm_bf16split_kernel<false, false><<<dim3(mblocks, 2), 256, 0, stream>>>(
        Q, W2h, W2l, P, N, 256, 256, nullptr);
    aggregate_vec_kernel<256, true, true><<<agg_grid, 256, 0, stream>>>(
        P, offsets, csr, dis, b2, Q, N);

    // Layer 3: P = Q @ W3 [N=128]; Z = agg(P) + b3
    gemm_bf16split_kernel<false, false><<<dim3(mblocks, 1), 256, 0, stream>>>(
        Q, W3h, W3l, P, N, 128, 256, nullptr);
    float* Z = Q;
    aggregate_vec_kernel<128, true, false><<<agg_grid, 256, 0, stream>>>(
        P, offsets, csr, dis, b3, Z, N);

    // Decode
    decode_kernel<<<(2 * N_EVAL + 15) / 16, 256, 0, stream>>>(Z, pos, neg, out);
}